// Round 8
// baseline (324.750 us; speedup 1.0000x reference)
//
#include <hip/hip_runtime.h>
#include <math.h>

#define N_NODES 50000
#define N_EDGES 800000
#define EMBED 256
#define HID 128
#define OUTD 12
#define N_TGT 4096

#define SCAN_NB 196  // ceil(50000/256)

typedef short bf16x8 __attribute__((ext_vector_type(8)));
typedef float f32x4 __attribute__((ext_vector_type(4)));

// f32 -> bf16 round-to-nearest-even (bit-exact, deterministic)
__device__ __forceinline__ unsigned short f2b(float f) {
    union { float f; unsigned int u; } v;
    v.f = f;
    unsigned int u = v.u;
    return (unsigned short)((u + 0x7FFFu + ((u >> 16) & 1u)) >> 16);
}

__device__ __forceinline__ float b2f(unsigned short s) {
    union { unsigned int u; float f; } v;
    v.u = ((unsigned int)s) << 16;
    return v.f;
}

// ---------------- CSR build ----------------
__global__ void k_hist(const int* __restrict__ dst, int* __restrict__ counts, int nE) {
    int i = blockIdx.x * 256 + threadIdx.x;
    if (i < nE) atomicAdd(&counts[dst[i]], 1);
}

__global__ __launch_bounds__(256) void k_scan_part(const int* __restrict__ counts,
                                                   int* __restrict__ partials) {
    __shared__ int ws[4];
    int i = blockIdx.x * 256 + threadIdx.x;
    int v = (i < N_NODES) ? counts[i] : 0;
#pragma unroll
    for (int off = 32; off > 0; off >>= 1) v += __shfl_down(v, off);
    int wid = threadIdx.x >> 6;
    if ((threadIdx.x & 63) == 0) ws[wid] = v;
    __syncthreads();
    if (threadIdx.x == 0) partials[blockIdx.x] = ws[0] + ws[1] + ws[2] + ws[3];
}

__global__ __launch_bounds__(256) void k_scan_top(int* __restrict__ partials) {
    __shared__ int s[256];
    int tid = threadIdx.x;
    int v = (tid < SCAN_NB) ? partials[tid] : 0;
    s[tid] = v;
    __syncthreads();
#pragma unroll
    for (int off = 1; off < 256; off <<= 1) {
        int t = (tid >= off) ? s[tid - off] : 0;
        __syncthreads();
        s[tid] += t;
        __syncthreads();
    }
    if (tid < SCAN_NB) partials[tid] = s[tid] - v;  // exclusive
}

__global__ __launch_bounds__(256) void k_scan_final(const int* __restrict__ counts,
                                                    const int* __restrict__ partials,
                                                    int* __restrict__ rowptr,
                                                    int* __restrict__ cursor,
                                                    float* __restrict__ dinv) {
    __shared__ int s[256];
    int tid = threadIdx.x;
    int i = blockIdx.x * 256 + tid;
    int c = (i < N_NODES) ? counts[i] : 0;
    s[tid] = c;
    __syncthreads();
#pragma unroll
    for (int off = 1; off < 256; off <<= 1) {
        int t = (tid >= off) ? s[tid - off] : 0;
        __syncthreads();
        s[tid] += t;
        __syncthreads();
    }
    if (i < N_NODES) {
        int rp = partials[blockIdx.x] + s[tid] - c;  // exclusive
        rowptr[i] = rp;
        cursor[i] = rp;
        dinv[i] = rsqrtf(1.0f + (float)c);
    }
}

__global__ void k_fill(const int* __restrict__ src, const int* __restrict__ dst,
                       int* __restrict__ cursor, int* __restrict__ col, int nE) {
    int i = blockIdx.x * 256 + threadIdx.x;
    if (i < nE) {
        int pos = atomicAdd(&cursor[dst[i]], 1);
        col[pos] = src[i];
    }
}

// one WAVE per row, 64-lane bitonic sort in registers (determinism canonicalizer)
__global__ __launch_bounds__(256) void k_sort_rows(const int* __restrict__ rowptr,
                                                   const int* __restrict__ counts,
                                                   int* __restrict__ col) {
    int wid = threadIdx.x >> 6;
    int lane = threadIdx.x & 63;
    int v = blockIdx.x * 4 + wid;
    if (v >= N_NODES) return;
    int beg = rowptr[v], cnt = counts[v];
    if (cnt <= 1) return;
    if (cnt <= 64) {
        int key = (lane < cnt) ? col[beg + lane] : 0x7FFFFFFF;
#pragma unroll
        for (int k = 2; k <= 64; k <<= 1) {
#pragma unroll
            for (int j = k >> 1; j > 0; j >>= 1) {
                int other = __shfl_xor(key, j);
                bool up = ((lane & k) == 0);
                bool lower = ((lane & j) == 0);
                bool take_min = (lower == up);
                key = take_min ? min(key, other) : max(key, other);
            }
        }
        if (lane < cnt) col[beg + lane] = key;
    } else if (lane == 0) {
        for (int i = 1; i < cnt; ++i) {
            int key = col[beg + i];
            int j = i - 1;
            while (j >= 0 && col[beg + j] > key) {
                col[beg + j + 1] = col[beg + j];
                --j;
            }
            col[beg + j + 1] = key;
        }
    }
}

// ---------------- W[k][n] f32 -> Wt[n][k] bf16 (tiny, once per launch) ----------------
__global__ void k_convW(const float* __restrict__ W, unsigned short* __restrict__ Wt, int K) {
    int i = blockIdx.x * 256 + threadIdx.x;
    if (i >= 128 * K) return;
    int n = i / K;
    int k = i - n * K;
    Wt[(size_t)n * K + k] = f2b(W[(size_t)k * 128 + n]);
}

// ---------------- bf16 MFMA GEMM: Hb[n][128] (bf16) = X[n][K] @ W[K][128] ----------------
// 256 threads = 4 waves (2x2), tile 128x128, BK=32. A staged to LDS (f32->bf16
// in-register, padded stride 40 -> conflict-free ds_read_b128). B frags read
// directly from L2-hot Wt[n][k]. C/D layout: col=lane&15, row=(lane>>4)*4+reg.
// Epilogue rounds acc to bf16 (halves gather traffic of downstream agg).
template <int K>
__global__ __launch_bounds__(256) void k_gemm_mfma(const float* __restrict__ X,
                                                   const unsigned short* __restrict__ Wt,
                                                   unsigned short* __restrict__ Hb, int n) {
    __shared__ unsigned short As[128 * 40];
    const int tid = threadIdx.x;
    const int row0 = blockIdx.x * 128;
    const int w = tid >> 6, lane = tid & 63;
    const int wm = w >> 1, wn = w & 1;
    const int lr = lane & 15, lg = lane >> 4;
    f32x4 acc[4][4] = {};
    for (int k0 = 0; k0 < K; k0 += 32) {
        __syncthreads();  // protect previous tile's frag reads
#pragma unroll
        for (int i = 0; i < 4; ++i) {
            int s = i * 256 + tid;          // 0..1023 float4 slots (128 rows x 8)
            int r = s >> 3, c4 = (s & 7) * 4;
            int gr = row0 + r;
            float4 v = make_float4(0.f, 0.f, 0.f, 0.f);
            if (gr < n) v = *(const float4*)&X[(size_t)gr * K + k0 + c4];
            ushort4 pk = make_ushort4(f2b(v.x), f2b(v.y), f2b(v.z), f2b(v.w));
            *(ushort4*)&As[r * 40 + c4] = pk;
        }
        __syncthreads();
        bf16x8 bfr[4];
#pragma unroll
        for (int fn = 0; fn < 4; ++fn) {
            int colg = wn * 64 + fn * 16 + lr;
            bfr[fn] = *(const bf16x8*)&Wt[(size_t)colg * K + k0 + lg * 8];
        }
#pragma unroll
        for (int fm = 0; fm < 4; ++fm) {
            int rloc = wm * 64 + fm * 16 + lr;
            bf16x8 afr = *(const bf16x8*)&As[rloc * 40 + lg * 8];
#pragma unroll
            for (int fn = 0; fn < 4; ++fn)
                acc[fm][fn] = __builtin_amdgcn_mfma_f32_16x16x32_bf16(
                    afr, bfr[fn], acc[fm][fn], 0, 0, 0);
        }
    }
#pragma unroll
    for (int fm = 0; fm < 4; ++fm) {
        int rbase = row0 + wm * 64 + fm * 16 + lg * 4;
#pragma unroll
        for (int r = 0; r < 4; ++r) {
            int gr = rbase + r;
            if (gr < n) {
#pragma unroll
                for (int fn = 0; fn < 4; ++fn)
                    Hb[(size_t)gr * 128 + wn * 64 + fn * 16 + lr] = f2b(acc[fm][fn][r]);
            }
        }
    }
}

// ---------------- fused CSR aggregation (bf16 gather) + self-loop + bias + ReLU ----------------
__global__ __launch_bounds__(256) void k_agg_csr(const unsigned short* __restrict__ h,
                                                 const int* __restrict__ rowptr,
                                                 const int* __restrict__ counts,
                                                 const int* __restrict__ col,
                                                 const float* __restrict__ dinv,
                                                 const float* __restrict__ b,
                                                 float* __restrict__ out) {
    int t = blockIdx.x * 256 + threadIdx.x;
    int v = t >> 5;
    int lane = t & 31;
    if (v >= N_NODES) return;
    float dv = dinv[v];
    ushort4 hv = *(const ushort4*)&h[(size_t)v * HID + lane * 4];
    float sl = dv * dv;
    float4 acc = make_float4(b2f(hv.x) * sl, b2f(hv.y) * sl, b2f(hv.z) * sl, b2f(hv.w) * sl);
    int beg = rowptr[v];
    int cnt = counts[v];
    for (int j = 0; j < cnt; ++j) {
        int s = col[beg + j];
        float w = dinv[s] * dv;
        ushort4 m = *(const ushort4*)&h[(size_t)s * HID + lane * 4];
        acc.x = fmaf(b2f(m.x), w, acc.x);
        acc.y = fmaf(b2f(m.y), w, acc.y);
        acc.z = fmaf(b2f(m.z), w, acc.z);
        acc.w = fmaf(b2f(m.w), w, acc.w);
    }
    float4 bv = *(const float4*)&b[lane * 4];
    acc.x = fmaxf(acc.x + bv.x, 0.f);
    acc.y = fmaxf(acc.y + bv.y, 0.f);
    acc.z = fmaxf(acc.z + bv.z, 0.f);
    acc.w = fmaxf(acc.w + bv.w, 0.f);
    *(float4*)&out[(size_t)v * HID + lane * 4] = acc;
}

// ---------------- final readout ----------------
__global__ void k_final(const float* __restrict__ h, const int* __restrict__ mask,
                        const float* __restrict__ Wr, const float* __restrict__ br,
                        float* __restrict__ out) {
    int t = blockIdx.x;
    int lane = threadIdx.x;
    int node = mask[t];
    float2 hv = *(const float2*)&h[(size_t)node * HID + lane * 2];
#pragma unroll
    for (int j = 0; j < OUTD; ++j) {
        float p = hv.x * Wr[(lane * 2) * OUTD + j] + hv.y * Wr[(lane * 2 + 1) * OUTD + j];
#pragma unroll
        for (int off = 32; off > 0; off >>= 1) p += __shfl_down(p, off);
        if (lane == 0) out[t * OUTD + j] = p + br[j];
    }
}

extern "C" void kernel_launch(void* const* d_in, const int* in_sizes, int n_in,
                              void* d_out, int out_size, void* d_ws, size_t ws_size,
                              hipStream_t stream) {
    const float* x  = (const float*)d_in[0];
    const int*   ei = (const int*)d_in[1];
    const int*   tm = (const int*)d_in[2];
    const float* W1 = (const float*)d_in[3];
    const float* b1 = (const float*)d_in[4];
    const float* W2 = (const float*)d_in[5];
    const float* b2 = (const float*)d_in[6];
    const float* Wr = (const float*)d_in[7];
    const float* br = (const float*)d_in[8];
    float* out = (float*)d_out;

    const int* e_src = ei;
    const int* e_dst = ei + N_EDGES;

    // workspace layout — all ranges disjoint:
    //   dinv     [0x000000, 0x030D40)
    //   counts   [0x040000, 0x070D40)
    //   rowptr   [0x080000, 0x0B0D40)
    //   cursor   [0x0C0000, 0x0F0D40)
    //   partials [0x0F8000, 0x0F8310)
    //   col      [0x100000, 0x40D400)
    //   Wt1      [0x410000, 0x420000)  128x256 bf16
    //   Wt2      [0x430000, 0x438000)  128x128 bf16
    //   bufA(bf16) [0x500000, 0x1135000)  50000x128x2B = 12.8 MB
    //   bufB(f32)  [0x1200000, 0x2A35000) 50000x128x4B = 25.6 MB
    char* ws = (char*)d_ws;
    float*          dinv     = (float*)(ws + 0x000000);
    int*            counts   = (int*)  (ws + 0x040000);
    int*            rowptr   = (int*)  (ws + 0x080000);
    int*            cursor   = (int*)  (ws + 0x0C0000);
    int*            partials = (int*)  (ws + 0x0F8000);
    int*            col      = (int*)  (ws + 0x100000);
    unsigned short* Wt1      = (unsigned short*)(ws + 0x410000);
    unsigned short* Wt2      = (unsigned short*)(ws + 0x430000);
    unsigned short* bufA     = (unsigned short*)(ws + 0x500000);
    float*          bufB     = (float*)(ws + 0x1200000);

    const int NB_E    = (N_EDGES + 255) / 256;
    const int NB_AGG  = (N_NODES * 32 + 255) / 256;
    const int NB_MF   = (N_NODES + 127) / 128;
    const int NB_SORT = (N_NODES + 3) / 4;

    // ---- CSR build (by dst) + dinv + weight conversion ----
    hipMemsetAsync(counts, 0, N_NODES * sizeof(int), stream);
    k_hist<<<NB_E, 256, 0, stream>>>(e_dst, counts, N_EDGES);
    k_scan_part<<<SCAN_NB, 256, 0, stream>>>(counts, partials);
    k_scan_top<<<1, 256, 0, stream>>>(partials);
    k_scan_final<<<SCAN_NB, 256, 0, stream>>>(counts, partials, rowptr, cursor, dinv);
    k_fill<<<NB_E, 256, 0, stream>>>(e_src, e_dst, cursor, col, N_EDGES);
    k_sort_rows<<<NB_SORT, 256, 0, stream>>>(rowptr, counts, col);
    k_convW<<<(128 * EMBED + 255) / 256, 256, 0, stream>>>(W1, Wt1, EMBED);
    k_convW<<<(128 * HID + 255) / 256, 256, 0, stream>>>(W2, Wt2, HID);

    // ---- layer 1 ----
    k_gemm_mfma<EMBED><<<NB_MF, 256, 0, stream>>>(x, Wt1, bufA, N_NODES);
    k_agg_csr<<<NB_AGG, 256, 0, stream>>>(bufA, rowptr, counts, col, dinv, b1, bufB);

    // ---- layer 2 ----
    k_gemm_mfma<HID><<<NB_MF, 256, 0, stream>>>(bufB, Wt2, bufA, N_NODES);
    k_agg_csr<<<NB_AGG, 256, 0, stream>>>(bufA, rowptr, counts, col, dinv, b2, bufB);

    // ---- readout ----
    k_final<<<N_TGT, 64, 0, stream>>>(bufB, tm, Wr, br, out);
}

// Round 9
// 242.009 us; speedup vs baseline: 1.3419x; 1.3419x over previous
//
#include <hip/hip_runtime.h>
#include <math.h>

#define N_NODES 50000
#define N_EDGES 800000
#define EMBED 256
#define HID 128
#define OUTD 12
#define N_TGT 4096

#define SCAN_NB 196  // ceil(50000/256)

typedef short bf16x8 __attribute__((ext_vector_type(8)));
typedef float f32x4 __attribute__((ext_vector_type(4)));

// f32 -> bf16 round-to-nearest-even (bit-exact, deterministic)
__device__ __forceinline__ unsigned short f2b(float f) {
    union { float f; unsigned int u; } v;
    v.f = f;
    unsigned int u = v.u;
    return (unsigned short)((u + 0x7FFFu + ((u >> 16) & 1u)) >> 16);
}

__device__ __forceinline__ float b2f(unsigned short s) {
    union { unsigned int u; float f; } v;
    v.u = ((unsigned int)s) << 16;
    return v.f;
}

// ---------------- CSR build ----------------
__global__ void k_hist(const int* __restrict__ dst, int* __restrict__ counts, int nE) {
    int i = blockIdx.x * 256 + threadIdx.x;
    if (i < nE) atomicAdd(&counts[dst[i]], 1);
}

__global__ __launch_bounds__(256) void k_scan_part(const int* __restrict__ counts,
                                                   int* __restrict__ partials) {
    __shared__ int ws[4];
    int i = blockIdx.x * 256 + threadIdx.x;
    int v = (i < N_NODES) ? counts[i] : 0;
#pragma unroll
    for (int off = 32; off > 0; off >>= 1) v += __shfl_down(v, off);
    int wid = threadIdx.x >> 6;
    if ((threadIdx.x & 63) == 0) ws[wid] = v;
    __syncthreads();
    if (threadIdx.x == 0) partials[blockIdx.x] = ws[0] + ws[1] + ws[2] + ws[3];
}

__global__ __launch_bounds__(256) void k_scan_top(int* __restrict__ partials) {
    __shared__ int s[256];
    int tid = threadIdx.x;
    int v = (tid < SCAN_NB) ? partials[tid] : 0;
    s[tid] = v;
    __syncthreads();
#pragma unroll
    for (int off = 1; off < 256; off <<= 1) {
        int t = (tid >= off) ? s[tid - off] : 0;
        __syncthreads();
        s[tid] += t;
        __syncthreads();
    }
    if (tid < SCAN_NB) partials[tid] = s[tid] - v;  // exclusive
}

__global__ __launch_bounds__(256) void k_scan_final(const int* __restrict__ counts,
                                                    const int* __restrict__ partials,
                                                    int* __restrict__ rowptr,
                                                    int* __restrict__ cursor,
                                                    float* __restrict__ dinv) {
    __shared__ int s[256];
    int tid = threadIdx.x;
    int i = blockIdx.x * 256 + tid;
    int c = (i < N_NODES) ? counts[i] : 0;
    s[tid] = c;
    __syncthreads();
#pragma unroll
    for (int off = 1; off < 256; off <<= 1) {
        int t = (tid >= off) ? s[tid - off] : 0;
        __syncthreads();
        s[tid] += t;
        __syncthreads();
    }
    if (i < N_NODES) {
        int rp = partials[blockIdx.x] + s[tid] - c;  // exclusive
        rowptr[i] = rp;
        cursor[i] = rp;
        dinv[i] = rsqrtf(1.0f + (float)c);
    }
}

__global__ void k_fill(const int* __restrict__ src, const int* __restrict__ dst,
                       int* __restrict__ cursor, int* __restrict__ col, int nE) {
    int i = blockIdx.x * 256 + threadIdx.x;
    if (i < nE) {
        int pos = atomicAdd(&cursor[dst[i]], 1);
        col[pos] = src[i];
    }
}

// one WAVE per row, 64-lane bitonic sort in registers (determinism canonicalizer)
__global__ __launch_bounds__(256) void k_sort_rows(const int* __restrict__ rowptr,
                                                   const int* __restrict__ counts,
                                                   int* __restrict__ col) {
    int wid = threadIdx.x >> 6;
    int lane = threadIdx.x & 63;
    int v = blockIdx.x * 4 + wid;
    if (v >= N_NODES) return;
    int beg = rowptr[v], cnt = counts[v];
    if (cnt <= 1) return;
    if (cnt <= 64) {
        int key = (lane < cnt) ? col[beg + lane] : 0x7FFFFFFF;
#pragma unroll
        for (int k = 2; k <= 64; k <<= 1) {
#pragma unroll
            for (int j = k >> 1; j > 0; j >>= 1) {
                int other = __shfl_xor(key, j);
                bool up = ((lane & k) == 0);
                bool lower = ((lane & j) == 0);
                bool take_min = (lower == up);
                key = take_min ? min(key, other) : max(key, other);
            }
        }
        if (lane < cnt) col[beg + lane] = key;
    } else if (lane == 0) {
        for (int i = 1; i < cnt; ++i) {
            int key = col[beg + i];
            int j = i - 1;
            while (j >= 0 && col[beg + j] > key) {
                col[beg + j + 1] = col[beg + j];
                --j;
            }
            col[beg + j + 1] = key;
        }
    }
}

// ---------------- W[k][n] f32 -> Wt[n][k] bf16 (tiny, once per launch) ----------------
__global__ void k_convW(const float* __restrict__ W, unsigned short* __restrict__ Wt, int K) {
    int i = blockIdx.x * 256 + threadIdx.x;
    if (i >= 128 * K) return;
    int n = i / K;
    int k = i - n * K;
    Wt[(size_t)n * K + k] = f2b(W[(size_t)k * 128 + n]);
}

// ---------------- bf16 MFMA GEMM: Hb[n][128] (bf16) = X[n][K] @ W[K][128] ----------------
template <int K>
__global__ __launch_bounds__(256) void k_gemm_mfma(const float* __restrict__ X,
                                                   const unsigned short* __restrict__ Wt,
                                                   unsigned short* __restrict__ Hb, int n) {
    __shared__ unsigned short As[128 * 40];
    const int tid = threadIdx.x;
    const int row0 = blockIdx.x * 128;
    const int w = tid >> 6, lane = tid & 63;
    const int wm = w >> 1, wn = w & 1;
    const int lr = lane & 15, lg = lane >> 4;
    f32x4 acc[4][4] = {};
    for (int k0 = 0; k0 < K; k0 += 32) {
        __syncthreads();  // protect previous tile's frag reads
#pragma unroll
        for (int i = 0; i < 4; ++i) {
            int s = i * 256 + tid;          // 0..1023 float4 slots (128 rows x 8)
            int r = s >> 3, c4 = (s & 7) * 4;
            int gr = row0 + r;
            float4 v = make_float4(0.f, 0.f, 0.f, 0.f);
            if (gr < n) v = *(const float4*)&X[(size_t)gr * K + k0 + c4];
            ushort4 pk = make_ushort4(f2b(v.x), f2b(v.y), f2b(v.z), f2b(v.w));
            *(ushort4*)&As[r * 40 + c4] = pk;
        }
        __syncthreads();
        bf16x8 bfr[4];
#pragma unroll
        for (int fn = 0; fn < 4; ++fn) {
            int colg = wn * 64 + fn * 16 + lr;
            bfr[fn] = *(const bf16x8*)&Wt[(size_t)colg * K + k0 + lg * 8];
        }
#pragma unroll
        for (int fm = 0; fm < 4; ++fm) {
            int rloc = wm * 64 + fm * 16 + lr;
            bf16x8 afr = *(const bf16x8*)&As[rloc * 40 + lg * 8];
#pragma unroll
            for (int fn = 0; fn < 4; ++fn)
                acc[fm][fn] = __builtin_amdgcn_mfma_f32_16x16x32_bf16(
                    afr, bfr[fn], acc[fm][fn], 0, 0, 0);
        }
    }
#pragma unroll
    for (int fm = 0; fm < 4; ++fm) {
        int rbase = row0 + wm * 64 + fm * 16 + lg * 4;
#pragma unroll
        for (int r = 0; r < 4; ++r) {
            int gr = rbase + r;
            if (gr < n) {
#pragma unroll
                for (int fn = 0; fn < 4; ++fn)
                    Hb[(size_t)gr * 128 + wn * 64 + fn * 16 + lr] = f2b(acc[fm][fn][r]);
            }
        }
    }
}

// ---------------- fused CSR aggregation, MLP-restructured ----------------
// Halfwave (32 lanes) per node. Per 32-neighbor chunk: coalesced col[] load +
// 32 parallel dinv gathers, then s/w broadcast by shfl (no memory). Gather loop
// unrolled 4x into 4 independent FMA chains (fixed combine order -> deterministic).
__global__ __launch_bounds__(256) void k_agg_csr(const unsigned short* __restrict__ h,
                                                 const int* __restrict__ rowptr,
                                                 const int* __restrict__ counts,
                                                 const int* __restrict__ col,
                                                 const float* __restrict__ dinv,
                                                 const float* __restrict__ b,
                                                 float* __restrict__ out) {
    int t = blockIdx.x * 256 + threadIdx.x;
    int v = t >> 5;
    int lane = t & 31;
    if (v >= N_NODES) return;
    float dv = dinv[v];
    ushort4 hv = *(const ushort4*)&h[(size_t)v * HID + lane * 4];
    float sl = dv * dv;
    f32x4 a0 = {b2f(hv.x) * sl, b2f(hv.y) * sl, b2f(hv.z) * sl, b2f(hv.w) * sl};
    f32x4 a1 = {0.f, 0.f, 0.f, 0.f}, a2 = a1, a3 = a1;
    int beg = rowptr[v];
    int cnt = counts[v];
    for (int j0 = 0; j0 < cnt; j0 += 32) {
        int m = cnt - j0; if (m > 32) m = 32;
        int sj = 0; float wj = 0.f;
        if (lane < m) {
            sj = col[beg + j0 + lane];       // coalesced
            wj = dinv[sj] * dv;              // 32 parallel random 4B gathers
        }
        int jj = 0;
        for (; jj + 4 <= m; jj += 4) {
            int s0 = __shfl(sj, jj + 0, 32), s1 = __shfl(sj, jj + 1, 32);
            int s2 = __shfl(sj, jj + 2, 32), s3 = __shfl(sj, jj + 3, 32);
            float w0 = __shfl(wj, jj + 0, 32), w1 = __shfl(wj, jj + 1, 32);
            float w2 = __shfl(wj, jj + 2, 32), w3 = __shfl(wj, jj + 3, 32);
            ushort4 m0 = *(const ushort4*)&h[(size_t)s0 * HID + lane * 4];
            ushort4 m1 = *(const ushort4*)&h[(size_t)s1 * HID + lane * 4];
            ushort4 m2 = *(const ushort4*)&h[(size_t)s2 * HID + lane * 4];
            ushort4 m3 = *(const ushort4*)&h[(size_t)s3 * HID + lane * 4];
            a0[0] = fmaf(b2f(m0.x), w0, a0[0]); a0[1] = fmaf(b2f(m0.y), w0, a0[1]);
            a0[2] = fmaf(b2f(m0.z), w0, a0[2]); a0[3] = fmaf(b2f(m0.w), w0, a0[3]);
            a1[0] = fmaf(b2f(m1.x), w1, a1[0]); a1[1] = fmaf(b2f(m1.y), w1, a1[1]);
            a1[2] = fmaf(b2f(m1.z), w1, a1[2]); a1[3] = fmaf(b2f(m1.w), w1, a1[3]);
            a2[0] = fmaf(b2f(m2.x), w2, a2[0]); a2[1] = fmaf(b2f(m2.y), w2, a2[1]);
            a2[2] = fmaf(b2f(m2.z), w2, a2[2]); a2[3] = fmaf(b2f(m2.w), w2, a2[3]);
            a3[0] = fmaf(b2f(m3.x), w3, a3[0]); a3[1] = fmaf(b2f(m3.y), w3, a3[1]);
            a3[2] = fmaf(b2f(m3.z), w3, a3[2]); a3[3] = fmaf(b2f(m3.w), w3, a3[3]);
        }
        for (; jj < m; ++jj) {
            int s0 = __shfl(sj, jj, 32);
            float w0 = __shfl(wj, jj, 32);
            ushort4 m0 = *(const ushort4*)&h[(size_t)s0 * HID + lane * 4];
            a0[0] = fmaf(b2f(m0.x), w0, a0[0]); a0[1] = fmaf(b2f(m0.y), w0, a0[1]);
            a0[2] = fmaf(b2f(m0.z), w0, a0[2]); a0[3] = fmaf(b2f(m0.w), w0, a0[3]);
        }
    }
    float4 bv = *(const float4*)&b[lane * 4];
    float4 r;
    r.x = fmaxf((a0[0] + a1[0]) + (a2[0] + a3[0]) + bv.x, 0.f);
    r.y = fmaxf((a0[1] + a1[1]) + (a2[1] + a3[1]) + bv.y, 0.f);
    r.z = fmaxf((a0[2] + a1[2]) + (a2[2] + a3[2]) + bv.z, 0.f);
    r.w = fmaxf((a0[3] + a1[3]) + (a2[3] + a3[3]) + bv.w, 0.f);
    *(float4*)&out[(size_t)v * HID + lane * 4] = r;
}

// ---------------- final readout ----------------
__global__ void k_final(const float* __restrict__ h, const int* __restrict__ mask,
                        const float* __restrict__ Wr, const float* __restrict__ br,
                        float* __restrict__ out) {
    int t = blockIdx.x;
    int lane = threadIdx.x;
    int node = mask[t];
    float2 hv = *(const float2*)&h[(size_t)node * HID + lane * 2];
#pragma unroll
    for (int j = 0; j < OUTD; ++j) {
        float p = hv.x * Wr[(lane * 2) * OUTD + j] + hv.y * Wr[(lane * 2 + 1) * OUTD + j];
#pragma unroll
        for (int off = 32; off > 0; off >>= 1) p += __shfl_down(p, off);
        if (lane == 0) out[t * OUTD + j] = p + br[j];
    }
}

extern "C" void kernel_launch(void* const* d_in, const int* in_sizes, int n_in,
                              void* d_out, int out_size, void* d_ws, size_t ws_size,
                              hipStream_t stream) {
    const float* x  = (const float*)d_in[0];
    const int*   ei = (const int*)d_in[1];
    const int*   tm = (const int*)d_in[2];
    const float* W1 = (const float*)d_in[3];
    const float* b1 = (const float*)d_in[4];
    const float* W2 = (const float*)d_in[5];
    const float* b2 = (const float*)d_in[6];
    const float* Wr = (const float*)d_in[7];
    const float* br = (const float*)d_in[8];
    float* out = (float*)d_out;

    const int* e_src = ei;
    const int* e_dst = ei + N_EDGES;

    // workspace layout — all ranges disjoint:
    //   dinv     [0x000000, 0x030D40)
    //   counts   [0x040000, 0x070D40)
    //   rowptr   [0x080000, 0x0B0D40)
    //   cursor   [0x0C0000, 0x0F0D40)
    //   partials [0x0F8000, 0x0F8310)
    //   col      [0x100000, 0x40D400)
    //   Wt1      [0x410000, 0x420000)  128x256 bf16
    //   Wt2      [0x430000, 0x438000)  128x128 bf16
    //   bufA(bf16) [0x500000, ...)  12.8 MB
    //   bufB(f32)  [0x1200000, ...) 25.6 MB
    char* ws = (char*)d_ws;
    float*          dinv     = (float*)(ws + 0x000000);
    int*            counts   = (int*)  (ws + 0x040000);
    int*            rowptr   = (int*)  (ws + 0x080000);
    int*            cursor   = (int*)  (ws + 0x0C0000);
    int*            partials = (int*)  (ws + 0x0F8000);
    int*            col      = (int*)  (ws + 0x100000);
    unsigned short* Wt1      = (unsigned short*)(ws + 0x410000);
    unsigned short* Wt2      = (unsigned short*)(ws + 0x430000);
    unsigned short* bufA     = (unsigned short*)(ws + 0x500000);
    float*          bufB     = (float*)(ws + 0x1200000);

    const int NB_E    = (N_EDGES + 255) / 256;
    const int NB_AGG  = (N_NODES * 32 + 255) / 256;
    const int NB_MF   = (N_NODES + 127) / 128;
    const int NB_SORT = (N_NODES + 3) / 4;

    // ---- CSR build (by dst) + dinv + weight conversion ----
    hipMemsetAsync(counts, 0, N_NODES * sizeof(int), stream);
    k_hist<<<NB_E, 256, 0, stream>>>(e_dst, counts, N_EDGES);
    k_scan_part<<<SCAN_NB, 256, 0, stream>>>(counts, partials);
    k_scan_top<<<1, 256, 0, stream>>>(partials);
    k_scan_final<<<SCAN_NB, 256, 0, stream>>>(counts, partials, rowptr, cursor, dinv);
    k_fill<<<NB_E, 256, 0, stream>>>(e_src, e_dst, cursor, col, N_EDGES);
    k_sort_rows<<<NB_SORT, 256, 0, stream>>>(rowptr, counts, col);
    k_convW<<<(128 * EMBED + 255) / 256, 256, 0, stream>>>(W1, Wt1, EMBED);
    k_convW<<<(128 * HID + 255) / 256, 256, 0, stream>>>(W2, Wt2, HID);

    // ---- layer 1 ----
    k_gemm_mfma<EMBED><<<NB_MF, 256, 0, stream>>>(x, Wt1, bufA, N_NODES);
    k_agg_csr<<<NB_AGG, 256, 0, stream>>>(bufA, rowptr, counts, col, dinv, b1, bufB);

    // ---- layer 2 ----
    k_gemm_mfma<HID><<<NB_MF, 256, 0, stream>>>(bufB, Wt2, bufA, N_NODES);
    k_agg_csr<<<NB_AGG, 256, 0, stream>>>(bufA, rowptr, counts, col, dinv, b2, bufB);

    // ---- readout ----
    k_final<<<N_TGT, 64, 0, stream>>>(bufB, tm, Wr, br, out);
}

// Round 10
// 226.312 us; speedup vs baseline: 1.4350x; 1.0694x over previous
//
#include <hip/hip_runtime.h>
#include <math.h>

#define N_NODES 50000
#define N_EDGES 800000
#define EMBED 256
#define HID 128
#define OUTD 12
#define N_TGT 4096

#define SCAN_NB 196   // ceil(50000/256)
#define NPART 8       // XCD count; blockIdx&7 ~ XCD id (round-robin dispatch)
#define NODES_PER_PART 6250  // 50000/8

typedef short bf16x8 __attribute__((ext_vector_type(8)));
typedef float f32x4 __attribute__((ext_vector_type(4)));

// f32 -> bf16 round-to-nearest-even (bit-exact, deterministic)
__device__ __forceinline__ unsigned short f2b(float f) {
    union { float f; unsigned int u; } v;
    v.f = f;
    unsigned int u = v.u;
    return (unsigned short)((u + 0x7FFFu + ((u >> 16) & 1u)) >> 16);
}

__device__ __forceinline__ float b2f(unsigned short s) {
    union { unsigned int u; float f; } v;
    v.u = ((unsigned int)s) << 16;
    return v.f;
}

// ---------------- CSR build (XCD-partitioned atomics) ----------------
// group g handles only dst in [g*6250,(g+1)*6250): all RMWs on a given
// counts/cursor/col region come from one XCD -> no L2 line ping-pong.
__global__ void k_hist(const int* __restrict__ dst, int* __restrict__ counts, int nE) {
    int g = blockIdx.x & (NPART - 1);
    int i = (blockIdx.x >> 3) * 256 + threadIdx.x;
    if (i >= nE) return;
    int d = dst[i];
    if ((unsigned)(d - g * NODES_PER_PART) < (unsigned)NODES_PER_PART)
        atomicAdd(&counts[d], 1);
}

__global__ void k_fill(const int* __restrict__ src, const int* __restrict__ dst,
                       int* __restrict__ cursor, int* __restrict__ col, int nE) {
    int g = blockIdx.x & (NPART - 1);
    int i = (blockIdx.x >> 3) * 256 + threadIdx.x;
    if (i >= nE) return;
    int d = dst[i];
    if ((unsigned)(d - g * NODES_PER_PART) < (unsigned)NODES_PER_PART) {
        int pos = atomicAdd(&cursor[d], 1);
        col[pos] = src[i];
    }
}

__global__ __launch_bounds__(256) void k_scan_part(const int* __restrict__ counts,
                                                   int* __restrict__ partials) {
    __shared__ int ws[4];
    int i = blockIdx.x * 256 + threadIdx.x;
    int v = (i < N_NODES) ? counts[i] : 0;
#pragma unroll
    for (int off = 32; off > 0; off >>= 1) v += __shfl_down(v, off);
    int wid = threadIdx.x >> 6;
    if ((threadIdx.x & 63) == 0) ws[wid] = v;
    __syncthreads();
    if (threadIdx.x == 0) partials[blockIdx.x] = ws[0] + ws[1] + ws[2] + ws[3];
}

__global__ __launch_bounds__(256) void k_scan_top(int* __restrict__ partials) {
    __shared__ int s[256];
    int tid = threadIdx.x;
    int v = (tid < SCAN_NB) ? partials[tid] : 0;
    s[tid] = v;
    __syncthreads();
#pragma unroll
    for (int off = 1; off < 256; off <<= 1) {
        int t = (tid >= off) ? s[tid - off] : 0;
        __syncthreads();
        s[tid] += t;
        __syncthreads();
    }
    if (tid < SCAN_NB) partials[tid] = s[tid] - v;  // exclusive
}

__global__ __launch_bounds__(256) void k_scan_final(const int* __restrict__ counts,
                                                    const int* __restrict__ partials,
                                                    int* __restrict__ rowptr,
                                                    int* __restrict__ cursor,
                                                    float* __restrict__ dinv) {
    __shared__ int s[256];
    int tid = threadIdx.x;
    int i = blockIdx.x * 256 + tid;
    int c = (i < N_NODES) ? counts[i] : 0;
    s[tid] = c;
    __syncthreads();
#pragma unroll
    for (int off = 1; off < 256; off <<= 1) {
        int t = (tid >= off) ? s[tid - off] : 0;
        __syncthreads();
        s[tid] += t;
        __syncthreads();
    }
    if (i < N_NODES) {
        int rp = partials[blockIdx.x] + s[tid] - c;  // exclusive
        rowptr[i] = rp;
        cursor[i] = rp;
        dinv[i] = rsqrtf(1.0f + (float)c);
    }
}

// one WAVE per row, 64-lane bitonic sort in registers (determinism canonicalizer)
__global__ __launch_bounds__(256) void k_sort_rows(const int* __restrict__ rowptr,
                                                   const int* __restrict__ counts,
                                                   int* __restrict__ col) {
    int wid = threadIdx.x >> 6;
    int lane = threadIdx.x & 63;
    int v = blockIdx.x * 4 + wid;
    if (v >= N_NODES) return;
    int beg = rowptr[v], cnt = counts[v];
    if (cnt <= 1) return;
    if (cnt <= 64) {
        int key = (lane < cnt) ? col[beg + lane] : 0x7FFFFFFF;
#pragma unroll
        for (int k = 2; k <= 64; k <<= 1) {
#pragma unroll
            for (int j = k >> 1; j > 0; j >>= 1) {
                int other = __shfl_xor(key, j);
                bool up = ((lane & k) == 0);
                bool lower = ((lane & j) == 0);
                bool take_min = (lower == up);
                key = take_min ? min(key, other) : max(key, other);
            }
        }
        if (lane < cnt) col[beg + lane] = key;
    } else if (lane == 0) {
        for (int i = 1; i < cnt; ++i) {
            int key = col[beg + i];
            int j = i - 1;
            while (j >= 0 && col[beg + j] > key) {
                col[beg + j + 1] = col[beg + j];
                --j;
            }
            col[beg + j + 1] = key;
        }
    }
}

// ---------------- W[k][n] f32 -> Wt[n][k] bf16 (tiny, once per launch) ----------------
__global__ void k_convW(const float* __restrict__ W, unsigned short* __restrict__ Wt, int K) {
    int i = blockIdx.x * 256 + threadIdx.x;
    if (i >= 128 * K) return;
    int n = i / K;
    int k = i - n * K;
    Wt[(size_t)n * K + k] = f2b(W[(size_t)k * 128 + n]);
}

// ---------------- bf16 MFMA GEMM: Hb[n][128] (bf16) = X[n][K] @ W[K][128] ----------------
template <int K>
__global__ __launch_bounds__(256) void k_gemm_mfma(const float* __restrict__ X,
                                                   const unsigned short* __restrict__ Wt,
                                                   unsigned short* __restrict__ Hb, int n) {
    __shared__ unsigned short As[128 * 40];
    const int tid = threadIdx.x;
    const int row0 = blockIdx.x * 128;
    const int w = tid >> 6, lane = tid & 63;
    const int wm = w >> 1, wn = w & 1;
    const int lr = lane & 15, lg = lane >> 4;
    f32x4 acc[4][4] = {};
    for (int k0 = 0; k0 < K; k0 += 32) {
        __syncthreads();  // protect previous tile's frag reads
#pragma unroll
        for (int i = 0; i < 4; ++i) {
            int s = i * 256 + tid;          // 0..1023 float4 slots (128 rows x 8)
            int r = s >> 3, c4 = (s & 7) * 4;
            int gr = row0 + r;
            float4 v = make_float4(0.f, 0.f, 0.f, 0.f);
            if (gr < n) v = *(const float4*)&X[(size_t)gr * K + k0 + c4];
            ushort4 pk = make_ushort4(f2b(v.x), f2b(v.y), f2b(v.z), f2b(v.w));
            *(ushort4*)&As[r * 40 + c4] = pk;
        }
        __syncthreads();
        bf16x8 bfr[4];
#pragma unroll
        for (int fn = 0; fn < 4; ++fn) {
            int colg = wn * 64 + fn * 16 + lr;
            bfr[fn] = *(const bf16x8*)&Wt[(size_t)colg * K + k0 + lg * 8];
        }
#pragma unroll
        for (int fm = 0; fm < 4; ++fm) {
            int rloc = wm * 64 + fm * 16 + lr;
            bf16x8 afr = *(const bf16x8*)&As[rloc * 40 + lg * 8];
#pragma unroll
            for (int fn = 0; fn < 4; ++fn)
                acc[fm][fn] = __builtin_amdgcn_mfma_f32_16x16x32_bf16(
                    afr, bfr[fn], acc[fm][fn], 0, 0, 0);
        }
    }
#pragma unroll
    for (int fm = 0; fm < 4; ++fm) {
        int rbase = row0 + wm * 64 + fm * 16 + lg * 4;
#pragma unroll
        for (int r = 0; r < 4; ++r) {
            int gr = rbase + r;
            if (gr < n) {
#pragma unroll
                for (int fn = 0; fn < 4; ++fn)
                    Hb[(size_t)gr * 128 + wn * 64 + fn * 16 + lr] = f2b(acc[fm][fn][r]);
            }
        }
    }
}

// ---------------- fused CSR aggregation, MLP-restructured ----------------
__global__ __launch_bounds__(256) void k_agg_csr(const unsigned short* __restrict__ h,
                                                 const int* __restrict__ rowptr,
                                                 const int* __restrict__ counts,
                                                 const int* __restrict__ col,
                                                 const float* __restrict__ dinv,
                                                 const float* __restrict__ b,
                                                 float* __restrict__ out) {
    int t = blockIdx.x * 256 + threadIdx.x;
    int v = t >> 5;
    int lane = t & 31;
    if (v >= N_NODES) return;
    float dv = dinv[v];
    ushort4 hv = *(const ushort4*)&h[(size_t)v * HID + lane * 4];
    float sl = dv * dv;
    f32x4 a0 = {b2f(hv.x) * sl, b2f(hv.y) * sl, b2f(hv.z) * sl, b2f(hv.w) * sl};
    f32x4 a1 = {0.f, 0.f, 0.f, 0.f}, a2 = a1, a3 = a1;
    int beg = rowptr[v];
    int cnt = counts[v];
    for (int j0 = 0; j0 < cnt; j0 += 32) {
        int m = cnt - j0; if (m > 32) m = 32;
        int sj = 0; float wj = 0.f;
        if (lane < m) {
            sj = col[beg + j0 + lane];       // coalesced
            wj = dinv[sj] * dv;              // 32 parallel random 4B gathers
        }
        int jj = 0;
        for (; jj + 4 <= m; jj += 4) {
            int s0 = __shfl(sj, jj + 0, 32), s1 = __shfl(sj, jj + 1, 32);
            int s2 = __shfl(sj, jj + 2, 32), s3 = __shfl(sj, jj + 3, 32);
            float w0 = __shfl(wj, jj + 0, 32), w1 = __shfl(wj, jj + 1, 32);
            float w2 = __shfl(wj, jj + 2, 32), w3 = __shfl(wj, jj + 3, 32);
            ushort4 m0 = *(const ushort4*)&h[(size_t)s0 * HID + lane * 4];
            ushort4 m1 = *(const ushort4*)&h[(size_t)s1 * HID + lane * 4];
            ushort4 m2 = *(const ushort4*)&h[(size_t)s2 * HID + lane * 4];
            ushort4 m3 = *(const ushort4*)&h[(size_t)s3 * HID + lane * 4];
            a0[0] = fmaf(b2f(m0.x), w0, a0[0]); a0[1] = fmaf(b2f(m0.y), w0, a0[1]);
            a0[2] = fmaf(b2f(m0.z), w0, a0[2]); a0[3] = fmaf(b2f(m0.w), w0, a0[3]);
            a1[0] = fmaf(b2f(m1.x), w1, a1[0]); a1[1] = fmaf(b2f(m1.y), w1, a1[1]);
            a1[2] = fmaf(b2f(m1.z), w1, a1[2]); a1[3] = fmaf(b2f(m1.w), w1, a1[3]);
            a2[0] = fmaf(b2f(m2.x), w2, a2[0]); a2[1] = fmaf(b2f(m2.y), w2, a2[1]);
            a2[2] = fmaf(b2f(m2.z), w2, a2[2]); a2[3] = fmaf(b2f(m2.w), w2, a2[3]);
            a3[0] = fmaf(b2f(m3.x), w3, a3[0]); a3[1] = fmaf(b2f(m3.y), w3, a3[1]);
            a3[2] = fmaf(b2f(m3.z), w3, a3[2]); a3[3] = fmaf(b2f(m3.w), w3, a3[3]);
        }
        for (; jj < m; ++jj) {
            int s0 = __shfl(sj, jj, 32);
            float w0 = __shfl(wj, jj, 32);
            ushort4 m0 = *(const ushort4*)&h[(size_t)s0 * HID + lane * 4];
            a0[0] = fmaf(b2f(m0.x), w0, a0[0]); a0[1] = fmaf(b2f(m0.y), w0, a0[1]);
            a0[2] = fmaf(b2f(m0.z), w0, a0[2]); a0[3] = fmaf(b2f(m0.w), w0, a0[3]);
        }
    }
    float4 bv = *(const float4*)&b[lane * 4];
    float4 r;
    r.x = fmaxf((a0[0] + a1[0]) + (a2[0] + a3[0]) + bv.x, 0.f);
    r.y = fmaxf((a0[1] + a1[1]) + (a2[1] + a3[1]) + bv.y, 0.f);
    r.z = fmaxf((a0[2] + a1[2]) + (a2[2] + a3[2]) + bv.z, 0.f);
    r.w = fmaxf((a0[3] + a1[3]) + (a2[3] + a3[3]) + bv.w, 0.f);
    *(float4*)&out[(size_t)v * HID + lane * 4] = r;
}

// ---------------- final readout ----------------
__global__ void k_final(const float* __restrict__ h, const int* __restrict__ mask,
                        const float* __restrict__ Wr, const float* __restrict__ br,
                        float* __restrict__ out) {
    int t = blockIdx.x;
    int lane = threadIdx.x;
    int node = mask[t];
    float2 hv = *(const float2*)&h[(size_t)node * HID + lane * 2];
#pragma unroll
    for (int j = 0; j < OUTD; ++j) {
        float p = hv.x * Wr[(lane * 2) * OUTD + j] + hv.y * Wr[(lane * 2 + 1) * OUTD + j];
#pragma unroll
        for (int off = 32; off > 0; off >>= 1) p += __shfl_down(p, off);
        if (lane == 0) out[t * OUTD + j] = p + br[j];
    }
}

extern "C" void kernel_launch(void* const* d_in, const int* in_sizes, int n_in,
                              void* d_out, int out_size, void* d_ws, size_t ws_size,
                              hipStream_t stream) {
    const float* x  = (const float*)d_in[0];
    const int*   ei = (const int*)d_in[1];
    const int*   tm = (const int*)d_in[2];
    const float* W1 = (const float*)d_in[3];
    const float* b1 = (const float*)d_in[4];
    const float* W2 = (const float*)d_in[5];
    const float* b2 = (const float*)d_in[6];
    const float* Wr = (const float*)d_in[7];
    const float* br = (const float*)d_in[8];
    float* out = (float*)d_out;

    const int* e_src = ei;
    const int* e_dst = ei + N_EDGES;

    // workspace layout — all ranges disjoint (see R4 postmortem):
    char* ws = (char*)d_ws;
    float*          dinv     = (float*)(ws + 0x000000);
    int*            counts   = (int*)  (ws + 0x040000);
    int*            rowptr   = (int*)  (ws + 0x080000);
    int*            cursor   = (int*)  (ws + 0x0C0000);
    int*            partials = (int*)  (ws + 0x0F8000);
    int*            col      = (int*)  (ws + 0x100000);
    unsigned short* Wt1      = (unsigned short*)(ws + 0x410000);
    unsigned short* Wt2      = (unsigned short*)(ws + 0x430000);
    unsigned short* bufA     = (unsigned short*)(ws + 0x500000);
    float*          bufB     = (float*)(ws + 0x1200000);

    const int NB_E    = (N_EDGES + 255) / 256;
    const int NB_EP   = NB_E * NPART;          // partitioned edge kernels
    const int NB_AGG  = (N_NODES * 32 + 255) / 256;
    const int NB_MF   = (N_NODES + 127) / 128;
    const int NB_SORT = (N_NODES + 3) / 4;

    // ---- CSR build (by dst, XCD-partitioned) + dinv + weight conversion ----
    hipMemsetAsync(counts, 0, N_NODES * sizeof(int), stream);
    k_hist<<<NB_EP, 256, 0, stream>>>(e_dst, counts, N_EDGES);
    k_scan_part<<<SCAN_NB, 256, 0, stream>>>(counts, partials);
    k_scan_top<<<1, 256, 0, stream>>>(partials);
    k_scan_final<<<SCAN_NB, 256, 0, stream>>>(counts, partials, rowptr, cursor, dinv);
    k_fill<<<NB_EP, 256, 0, stream>>>(e_src, e_dst, cursor, col, N_EDGES);
    k_sort_rows<<<NB_SORT, 256, 0, stream>>>(rowptr, counts, col);
    k_convW<<<(128 * EMBED + 255) / 256, 256, 0, stream>>>(W1, Wt1, EMBED);
    k_convW<<<(128 * HID + 255) / 256, 256, 0, stream>>>(W2, Wt2, HID);

    // ---- layer 1 ----
    k_gemm_mfma<EMBED><<<NB_MF, 256, 0, stream>>>(x, Wt1, bufA, N_NODES);
    k_agg_csr<<<NB_AGG, 256, 0, stream>>>(bufA, rowptr, counts, col, dinv, b1, bufB);

    // ---- layer 2 ----
    k_gemm_mfma<HID><<<NB_MF, 256, 0, stream>>>(bufB, Wt2, bufA, N_NODES);
    k_agg_csr<<<NB_AGG, 256, 0, stream>>>(bufA, rowptr, counts, col, dinv, b2, bufB);

    // ---- readout ----
    k_final<<<N_TGT, 64, 0, stream>>>(bufB, tm, Wr, br, out);
}

// Round 11
// 224.011 us; speedup vs baseline: 1.4497x; 1.0103x over previous
//
#include <hip/hip_runtime.h>
#include <math.h>

#define N_NODES 50000
#define N_EDGES 800000
#define EMBED 256
#define HID 128
#define OUTD 12
#define N_TGT 4096

#define SCAN_NB 196   // ceil(50000/256)
#define NPART 8       // XCD count; blockIdx&7 ~ XCD id (round-robin dispatch)
#define NODES_PER_PART 6250  // 50000/8

typedef short bf16x8 __attribute__((ext_vector_type(8)));
typedef float f32x4 __attribute__((ext_vector_type(4)));

// f32 -> bf16 round-to-nearest-even (bit-exact, deterministic)
__device__ __forceinline__ unsigned short f2b(float f) {
    union { float f; unsigned int u; } v;
    v.f = f;
    unsigned int u = v.u;
    return (unsigned short)((u + 0x7FFFu + ((u >> 16) & 1u)) >> 16);
}

__device__ __forceinline__ float b2f(unsigned short s) {
    union { unsigned int u; float f; } v;
    v.u = ((unsigned int)s) << 16;
    return v.f;
}

// ---------------- zero counts (rocclr fill kernel is 40us for 200KB!) ----------------
__global__ void k_zero(int* __restrict__ p, int n) {
    int i = blockIdx.x * 256 + threadIdx.x;
    if (i < n) p[i] = 0;
}

// ---------------- CSR build (XCD-partitioned atomics) ----------------
__global__ void k_hist(const int* __restrict__ dst, int* __restrict__ counts, int nE) {
    int g = blockIdx.x & (NPART - 1);
    int i = (blockIdx.x >> 3) * 256 + threadIdx.x;
    if (i >= nE) return;
    int d = dst[i];
    if ((unsigned)(d - g * NODES_PER_PART) < (unsigned)NODES_PER_PART)
        atomicAdd(&counts[d], 1);
}

__global__ void k_fill(const int* __restrict__ src, const int* __restrict__ dst,
                       int* __restrict__ cursor, int* __restrict__ col, int nE) {
    int g = blockIdx.x & (NPART - 1);
    int i = (blockIdx.x >> 3) * 256 + threadIdx.x;
    if (i >= nE) return;
    int d = dst[i];
    if ((unsigned)(d - g * NODES_PER_PART) < (unsigned)NODES_PER_PART) {
        int pos = atomicAdd(&cursor[d], 1);
        col[pos] = src[i];
    }
}

__global__ __launch_bounds__(256) void k_scan_part(const int* __restrict__ counts,
                                                   int* __restrict__ partials) {
    __shared__ int ws[4];
    int i = blockIdx.x * 256 + threadIdx.x;
    int v = (i < N_NODES) ? counts[i] : 0;
#pragma unroll
    for (int off = 32; off > 0; off >>= 1) v += __shfl_down(v, off);
    int wid = threadIdx.x >> 6;
    if ((threadIdx.x & 63) == 0) ws[wid] = v;
    __syncthreads();
    if (threadIdx.x == 0) partials[blockIdx.x] = ws[0] + ws[1] + ws[2] + ws[3];
}

__global__ __launch_bounds__(256) void k_scan_top(int* __restrict__ partials) {
    __shared__ int s[256];
    int tid = threadIdx.x;
    int v = (tid < SCAN_NB) ? partials[tid] : 0;
    s[tid] = v;
    __syncthreads();
#pragma unroll
    for (int off = 1; off < 256; off <<= 1) {
        int t = (tid >= off) ? s[tid - off] : 0;
        __syncthreads();
        s[tid] += t;
        __syncthreads();
    }
    if (tid < SCAN_NB) partials[tid] = s[tid] - v;  // exclusive
}

__global__ __launch_bounds__(256) void k_scan_final(const int* __restrict__ counts,
                                                    const int* __restrict__ partials,
                                                    int* __restrict__ rowptr,
                                                    int* __restrict__ cursor,
                                                    float* __restrict__ dinv) {
    __shared__ int s[256];
    int tid = threadIdx.x;
    int i = blockIdx.x * 256 + tid;
    int c = (i < N_NODES) ? counts[i] : 0;
    s[tid] = c;
    __syncthreads();
#pragma unroll
    for (int off = 1; off < 256; off <<= 1) {
        int t = (tid >= off) ? s[tid - off] : 0;
        __syncthreads();
        s[tid] += t;
        __syncthreads();
    }
    if (i < N_NODES) {
        int rp = partials[blockIdx.x] + s[tid] - c;  // exclusive
        rowptr[i] = rp;
        cursor[i] = rp;
        dinv[i] = rsqrtf(1.0f + (float)c);
    }
}

// one WAVE per row, 64-lane bitonic sort in registers (determinism canonicalizer)
__global__ __launch_bounds__(256) void k_sort_rows(const int* __restrict__ rowptr,
                                                   const int* __restrict__ counts,
                                                   int* __restrict__ col) {
    int wid = threadIdx.x >> 6;
    int lane = threadIdx.x & 63;
    int v = blockIdx.x * 4 + wid;
    if (v >= N_NODES) return;
    int beg = rowptr[v], cnt = counts[v];
    if (cnt <= 1) return;
    if (cnt <= 64) {
        int key = (lane < cnt) ? col[beg + lane] : 0x7FFFFFFF;
#pragma unroll
        for (int k = 2; k <= 64; k <<= 1) {
#pragma unroll
            for (int j = k >> 1; j > 0; j >>= 1) {
                int other = __shfl_xor(key, j);
                bool up = ((lane & k) == 0);
                bool lower = ((lane & j) == 0);
                bool take_min = (lower == up);
                key = take_min ? min(key, other) : max(key, other);
            }
        }
        if (lane < cnt) col[beg + lane] = key;
    } else if (lane == 0) {
        for (int i = 1; i < cnt; ++i) {
            int key = col[beg + i];
            int j = i - 1;
            while (j >= 0 && col[beg + j] > key) {
                col[beg + j + 1] = col[beg + j];
                --j;
            }
            col[beg + j + 1] = key;
        }
    }
}

// ---------------- W[k][n] f32 -> Wt[n][k] bf16 (tiny, once per launch) ----------------
__global__ void k_convW(const float* __restrict__ W, unsigned short* __restrict__ Wt, int K) {
    int i = blockIdx.x * 256 + threadIdx.x;
    if (i >= 128 * K) return;
    int n = i / K;
    int k = i - n * K;
    Wt[(size_t)n * K + k] = f2b(W[(size_t)k * 128 + n]);
}

// ---------------- bf16 MFMA GEMM: Hb[n][128] (bf16) = X[n][K] @ W[K][128] ----------------
// 64-row tile (grid 782 -> ~3 blocks/CU), 4 waves 2x2, wave = 32x64 out.
// Register-pipelined A staging: next k-tile's global loads issue right after
// the LDS write, overlapping HBM latency with B-loads + MFMAs. Per-output
// k-order identical to previous rounds -> bit-identical results.
template <int K>
__global__ __launch_bounds__(256) void k_gemm_mfma(const float* __restrict__ X,
                                                   const unsigned short* __restrict__ Wt,
                                                   unsigned short* __restrict__ Hb, int n) {
    __shared__ unsigned short As[64 * 40];
    const int tid = threadIdx.x;
    const int row0 = blockIdx.x * 64;
    const int w = tid >> 6, lane = tid & 63;
    const int wm = w >> 1, wn = w & 1;
    const int lr = lane & 15, lg = lane >> 4;

    // staging slots: 64 rows x 8 float4 = 512; 2 per thread
    int r0s = (tid * 2) >> 3, c0s = ((tid * 2) & 7) * 4;       // slot 2*tid
    int r1s = (tid * 2 + 1) >> 3, c1s = ((tid * 2 + 1) & 7) * 4;

    float4 sreg0 = make_float4(0.f, 0.f, 0.f, 0.f), sreg1 = sreg0;
    if (row0 + r0s < n) sreg0 = *(const float4*)&X[(size_t)(row0 + r0s) * K + c0s];
    if (row0 + r1s < n) sreg1 = *(const float4*)&X[(size_t)(row0 + r1s) * K + c1s];

    f32x4 acc[2][4] = {};
    for (int k0 = 0; k0 < K; k0 += 32) {
        __syncthreads();  // prev frag reads done before overwrite (no-op first iter)
        *(ushort4*)&As[r0s * 40 + c0s] =
            make_ushort4(f2b(sreg0.x), f2b(sreg0.y), f2b(sreg0.z), f2b(sreg0.w));
        *(ushort4*)&As[r1s * 40 + c1s] =
            make_ushort4(f2b(sreg1.x), f2b(sreg1.y), f2b(sreg1.z), f2b(sreg1.w));
        __syncthreads();
        // prefetch next k-tile (vmcnt drain happens at next iteration's LDS write)
        if (k0 + 32 < K) {
            sreg0 = make_float4(0.f, 0.f, 0.f, 0.f); sreg1 = sreg0;
            if (row0 + r0s < n) sreg0 = *(const float4*)&X[(size_t)(row0 + r0s) * K + k0 + 32 + c0s];
            if (row0 + r1s < n) sreg1 = *(const float4*)&X[(size_t)(row0 + r1s) * K + k0 + 32 + c1s];
        }
        bf16x8 bfr[4];
#pragma unroll
        for (int fn = 0; fn < 4; ++fn) {
            int colg = wn * 64 + fn * 16 + lr;
            bfr[fn] = *(const bf16x8*)&Wt[(size_t)colg * K + k0 + lg * 8];
        }
#pragma unroll
        for (int fm = 0; fm < 2; ++fm) {
            int rloc = wm * 32 + fm * 16 + lr;
            bf16x8 afr = *(const bf16x8*)&As[rloc * 40 + lg * 8];
#pragma unroll
            for (int fn = 0; fn < 4; ++fn)
                acc[fm][fn] = __builtin_amdgcn_mfma_f32_16x16x32_bf16(
                    afr, bfr[fn], acc[fm][fn], 0, 0, 0);
        }
    }
#pragma unroll
    for (int fm = 0; fm < 2; ++fm) {
        int rbase = row0 + wm * 32 + fm * 16 + lg * 4;
#pragma unroll
        for (int r = 0; r < 4; ++r) {
            int gr = rbase + r;
            if (gr < n) {
#pragma unroll
                for (int fn = 0; fn < 4; ++fn)
                    Hb[(size_t)gr * 128 + wn * 64 + fn * 16 + lr] = f2b(acc[fm][fn][r]);
            }
        }
    }
}

// ---------------- fused CSR aggregation, MLP-restructured ----------------
__global__ __launch_bounds__(256) void k_agg_csr(const unsigned short* __restrict__ h,
                                                 const int* __restrict__ rowptr,
                                                 const int* __restrict__ counts,
                                                 const int* __restrict__ col,
                                                 const float* __restrict__ dinv,
                                                 const float* __restrict__ b,
                                                 float* __restrict__ out) {
    int t = blockIdx.x * 256 + threadIdx.x;
    int v = t >> 5;
    int lane = t & 31;
    if (v >= N_NODES) return;
    float dv = dinv[v];
    ushort4 hv = *(const ushort4*)&h[(size_t)v * HID + lane * 4];
    float sl = dv * dv;
    f32x4 a0 = {b2f(hv.x) * sl, b2f(hv.y) * sl, b2f(hv.z) * sl, b2f(hv.w) * sl};
    f32x4 a1 = {0.f, 0.f, 0.f, 0.f}, a2 = a1, a3 = a1;
    int beg = rowptr[v];
    int cnt = counts[v];
    for (int j0 = 0; j0 < cnt; j0 += 32) {
        int m = cnt - j0; if (m > 32) m = 32;
        int sj = 0; float wj = 0.f;
        if (lane < m) {
            sj = col[beg + j0 + lane];       // coalesced
            wj = dinv[sj] * dv;              // 32 parallel random 4B gathers
        }
        int jj = 0;
        for (; jj + 4 <= m; jj += 4) {
            int s0 = __shfl(sj, jj + 0, 32), s1 = __shfl(sj, jj + 1, 32);
            int s2 = __shfl(sj, jj + 2, 32), s3 = __shfl(sj, jj + 3, 32);
            float w0 = __shfl(wj, jj + 0, 32), w1 = __shfl(wj, jj + 1, 32);
            float w2 = __shfl(wj, jj + 2, 32), w3 = __shfl(wj, jj + 3, 32);
            ushort4 m0 = *(const ushort4*)&h[(size_t)s0 * HID + lane * 4];
            ushort4 m1 = *(const ushort4*)&h[(size_t)s1 * HID + lane * 4];
            ushort4 m2 = *(const ushort4*)&h[(size_t)s2 * HID + lane * 4];
            ushort4 m3 = *(const ushort4*)&h[(size_t)s3 * HID + lane * 4];
            a0[0] = fmaf(b2f(m0.x), w0, a0[0]); a0[1] = fmaf(b2f(m0.y), w0, a0[1]);
            a0[2] = fmaf(b2f(m0.z), w0, a0[2]); a0[3] = fmaf(b2f(m0.w), w0, a0[3]);
            a1[0] = fmaf(b2f(m1.x), w1, a1[0]); a1[1] = fmaf(b2f(m1.y), w1, a1[1]);
            a1[2] = fmaf(b2f(m1.z), w1, a1[2]); a1[3] = fmaf(b2f(m1.w), w1, a1[3]);
            a2[0] = fmaf(b2f(m2.x), w2, a2[0]); a2[1] = fmaf(b2f(m2.y), w2, a2[1]);
            a2[2] = fmaf(b2f(m2.z), w2, a2[2]); a2[3] = fmaf(b2f(m2.w), w2, a2[3]);
            a3[0] = fmaf(b2f(m3.x), w3, a3[0]); a3[1] = fmaf(b2f(m3.y), w3, a3[1]);
            a3[2] = fmaf(b2f(m3.z), w3, a3[2]); a3[3] = fmaf(b2f(m3.w), w3, a3[3]);
        }
        for (; jj < m; ++jj) {
            int s0 = __shfl(sj, jj, 32);
            float w0 = __shfl(wj, jj, 32);
            ushort4 m0 = *(const ushort4*)&h[(size_t)s0 * HID + lane * 4];
            a0[0] = fmaf(b2f(m0.x), w0, a0[0]); a0[1] = fmaf(b2f(m0.y), w0, a0[1]);
            a0[2] = fmaf(b2f(m0.z), w0, a0[2]); a0[3] = fmaf(b2f(m0.w), w0, a0[3]);
        }
    }
    float4 bv = *(const float4*)&b[lane * 4];
    float4 r;
    r.x = fmaxf((a0[0] + a1[0]) + (a2[0] + a3[0]) + bv.x, 0.f);
    r.y = fmaxf((a0[1] + a1[1]) + (a2[1] + a3[1]) + bv.y, 0.f);
    r.z = fmaxf((a0[2] + a1[2]) + (a2[2] + a3[2]) + bv.z, 0.f);
    r.w = fmaxf((a0[3] + a1[3]) + (a2[3] + a3[3]) + bv.w, 0.f);
    *(float4*)&out[(size_t)v * HID + lane * 4] = r;
}

// ---------------- final readout ----------------
__global__ void k_final(const float* __restrict__ h, const int* __restrict__ mask,
                        const float* __restrict__ Wr, const float* __restrict__ br,
                        float* __restrict__ out) {
    int t = blockIdx.x;
    int lane = threadIdx.x;
    int node = mask[t];
    float2 hv = *(const float2*)&h[(size_t)node * HID + lane * 2];
#pragma unroll
    for (int j = 0; j < OUTD; ++j) {
        float p = hv.x * Wr[(lane * 2) * OUTD + j] + hv.y * Wr[(lane * 2 + 1) * OUTD + j];
#pragma unroll
        for (int off = 32; off > 0; off >>= 1) p += __shfl_down(p, off);
        if (lane == 0) out[t * OUTD + j] = p + br[j];
    }
}

extern "C" void kernel_launch(void* const* d_in, const int* in_sizes, int n_in,
                              void* d_out, int out_size, void* d_ws, size_t ws_size,
                              hipStream_t stream) {
    const float* x  = (const float*)d_in[0];
    const int*   ei = (const int*)d_in[1];
    const int*   tm = (const int*)d_in[2];
    const float* W1 = (const float*)d_in[3];
    const float* b1 = (const float*)d_in[4];
    const float* W2 = (const float*)d_in[5];
    const float* b2 = (const float*)d_in[6];
    const float* Wr = (const float*)d_in[7];
    const float* br = (const float*)d_in[8];
    float* out = (float*)d_out;

    const int* e_src = ei;
    const int* e_dst = ei + N_EDGES;

    // workspace layout — all ranges disjoint (see R4 postmortem):
    char* ws = (char*)d_ws;
    float*          dinv     = (float*)(ws + 0x000000);
    int*            counts   = (int*)  (ws + 0x040000);
    int*            rowptr   = (int*)  (ws + 0x080000);
    int*            cursor   = (int*)  (ws + 0x0C0000);
    int*            partials = (int*)  (ws + 0x0F8000);
    int*            col      = (int*)  (ws + 0x100000);
    unsigned short* Wt1      = (unsigned short*)(ws + 0x410000);
    unsigned short* Wt2      = (unsigned short*)(ws + 0x430000);
    unsigned short* bufA     = (unsigned short*)(ws + 0x500000);
    float*          bufB     = (float*)(ws + 0x1200000);

    const int NB_E    = (N_EDGES + 255) / 256;
    const int NB_EP   = NB_E * NPART;          // partitioned edge kernels
    const int NB_AGG  = (N_NODES * 32 + 255) / 256;
    const int NB_MF   = (N_NODES + 63) / 64;   // 64-row tiles
    const int NB_SORT = (N_NODES + 3) / 4;

    // ---- CSR build (by dst, XCD-partitioned) + dinv + weight conversion ----
    k_zero<<<SCAN_NB, 256, 0, stream>>>(counts, N_NODES);
    k_hist<<<NB_EP, 256, 0, stream>>>(e_dst, counts, N_EDGES);
    k_scan_part<<<SCAN_NB, 256, 0, stream>>>(counts, partials);
    k_scan_top<<<1, 256, 0, stream>>>(partials);
    k_scan_final<<<SCAN_NB, 256, 0, stream>>>(counts, partials, rowptr, cursor, dinv);
    k_fill<<<NB_EP, 256, 0, stream>>>(e_src, e_dst, cursor, col, N_EDGES);
    k_sort_rows<<<NB_SORT, 256, 0, stream>>>(rowptr, counts, col);
    k_convW<<<(128 * EMBED + 255) / 256, 256, 0, stream>>>(W1, Wt1, EMBED);
    k_convW<<<(128 * HID + 255) / 256, 256, 0, stream>>>(W2, Wt2, HID);

    // ---- layer 1 ----
    k_gemm_mfma<EMBED><<<NB_MF, 256, 0, stream>>>(x, Wt1, bufA, N_NODES);
    k_agg_csr<<<NB_AGG, 256, 0, stream>>>(bufA, rowptr, counts, col, dinv, b1, bufB);

    // ---- layer 2 ----
    k_gemm_mfma<HID><<<NB_MF, 256, 0, stream>>>(bufB, Wt2, bufA, N_NODES);
    k_agg_csr<<<NB_AGG, 256, 0, stream>>>(bufA, rowptr, counts, col, dinv, b2, bufB);

    // ---- readout ----
    k_final<<<N_TGT, 64, 0, stream>>>(bufB, tm, Wr, br, out);
}